// Round 1
// baseline (381.559 us; speedup 1.0000x reference)
//
#include <hip/hip_runtime.h>

#define BB 8
#define HH 512
#define WW 512
#define HW (HH * WW)
#define NPIX (BB * HH * WW)

__device__ __forceinline__ float clipf(float v) {
    // EPS = 1e-10; upper bound 1.0-1e-10 rounds to 1.0f in fp32.
    return fminf(fmaxf(v, 1e-10f), 1.0f);
}

__global__ void init_ws(double* ws) { ws[0] = 0.0; }

__global__ void finalize(const double* ws, float* out) { out[0] = (float)ws[0]; }

__global__ __launch_bounds__(256) void loss_kernel(
    const float* __restrict__ roi,
    const float* __restrict__ hm0,
    const float* __restrict__ hm1,
    const float* __restrict__ hm2,
    const float* __restrict__ r1pf, const float* __restrict__ r1pb,
    const float* __restrict__ r1nf, const float* __restrict__ r1nb,
    const float* __restrict__ r0f,  const float* __restrict__ r0b,
    const float* __restrict__ r2f,  const float* __restrict__ r2b,
    const float* __restrict__ fA,   // flow_0_1f  (unshifted operand)
    const float* __restrict__ fAi,  // flow_1_0b  (shifted operand)
    const float* __restrict__ fB,   // flow_1_2f  (unshifted operand)
    const float* __restrict__ fBi,  // flow_2_1b  (shifted operand)
    double* __restrict__ ws)
{
    int idx = blockIdx.x * blockDim.x + threadIdx.x;
    float acc = 0.0f;
    if (idx < NPIX) {
        int x = idx & (WW - 1);
        int y = (idx >> 9) & (HH - 1);
        int b = idx >> 18;

        float roiv = roi[idx];
        float h0 = hm0[idx], h1 = hm1[idx], h2 = hm2[idx];
        float pre  = fabsf(h0 - h1);
        float post = fabsf(h1 - h2);
        float w1 = roiv * (1.0f + pre);   // RF = 1.0
        float w2 = roiv * (1.0f + post);

        float d;
        float s1p = 0.f, s1n = 0.f, s0 = 0.f, s2 = 0.f;
        d = r1pf[idx] - h1; s1p += d * d;
        d = r1pb[idx] - h1; s1p += d * d;
        d = r1nf[idx] - h1; s1n += d * d;
        d = r1nb[idx] - h1; s1n += d * d;
        d = r0f[idx]  - h0; s0  += d * d;
        d = r0b[idx]  - h0; s0  += d * d;
        d = r2f[idx]  - h2; s2  += d * d;
        d = r2b[idx]  - h2; s2  += d * d;

        acc = 0.25f * (w1 * s1p + w2 * s1n) + 0.5f * (w1 * s0 + w2 * s2);

        // Flow consistency: 9 channels x 2 flow pairs.
        // Channel i: dy = {1,1,1,0,0,0,-1,-1,-1}[i], dx = {1,0,-1}[i%3].
        // a = flow[b, i, y, x]; bv = flow_inv[b, 8-i, y-dy, x-dx]; mask = roi[b,0,y,x].
        float cons = 0.0f;
        int flowBase = b * 9 * HW;   // channel 0 of this batch
        int aPix = y * WW + x;
        #pragma unroll
        for (int i = 0; i < 9; ++i) {
            const int dy = (i < 3) ? 1 : (i < 6) ? 0 : -1;
            const int m  = i % 3;
            const int dx = (m == 0) ? 1 : (m == 1) ? 0 : -1;
            bool valid = ((unsigned)(y - dy) < (unsigned)HH) &&
                         ((unsigned)(x - dx) < (unsigned)WW);
            int ys = valid ? (y - dy) : y;   // clamped (term zeroed below)
            int xs = valid ? (x - dx) : x;
            int bPix = ys * WW + xs;

            float a1 = fA [flowBase + i       * HW + aPix];
            float b1 = fAi[flowBase + (8 - i) * HW + bPix];
            float a2 = fB [flowBase + i       * HW + aPix];
            float b2 = fBi[flowBase + (8 - i) * HW + bPix];

            float d1 = clipf(a1) - clipf(b1);
            float d2 = clipf(a2) - clipf(b2);
            float vf = valid ? 1.0f : 0.0f;
            cons += vf * (d1 * d1 + d2 * d2);
        }
        acc += cons * roiv * (1.0f / 9.0f);
    }

    // Wave-64 reduction
    #pragma unroll
    for (int off = 32; off > 0; off >>= 1)
        acc += __shfl_down(acc, off, 64);

    __shared__ float wsum[4];
    int lane = threadIdx.x & 63;
    int wid  = threadIdx.x >> 6;
    if (lane == 0) wsum[wid] = acc;
    __syncthreads();
    if (threadIdx.x == 0) {
        float s = wsum[0] + wsum[1] + wsum[2] + wsum[3];
        atomicAdd(ws, (double)s);
    }
}

extern "C" void kernel_launch(void* const* d_in, const int* in_sizes, int n_in,
                              void* d_out, int out_size, void* d_ws, size_t ws_size,
                              hipStream_t stream) {
    const float* roi  = (const float*)d_in[0];
    // d_in[1] = boundary_mask: unused by the reference.
    const float* hm0  = (const float*)d_in[2];
    const float* hm1  = (const float*)d_in[3];
    const float* hm2  = (const float*)d_in[4];
    const float* r1pf = (const float*)d_in[5];
    const float* r1pb = (const float*)d_in[6];
    const float* r1nf = (const float*)d_in[7];
    const float* r1nb = (const float*)d_in[8];
    const float* r0f  = (const float*)d_in[9];
    const float* r0b  = (const float*)d_in[10];
    const float* r2f  = (const float*)d_in[11];
    const float* r2b  = (const float*)d_in[12];
    const float* fA   = (const float*)d_in[13];
    const float* fAi  = (const float*)d_in[14];
    const float* fB   = (const float*)d_in[15];
    const float* fBi  = (const float*)d_in[16];

    double* ws = (double*)d_ws;
    float* out = (float*)d_out;

    init_ws<<<1, 1, 0, stream>>>(ws);
    loss_kernel<<<NPIX / 256, 256, 0, stream>>>(
        roi, hm0, hm1, hm2, r1pf, r1pb, r1nf, r1nb,
        r0f, r0b, r2f, r2b, fA, fAi, fB, fBi, ws);
    finalize<<<1, 1, 0, stream>>>(ws, out);
}

// Round 2
// 368.262 us; speedup vs baseline: 1.0361x; 1.0361x over previous
//
#include <hip/hip_runtime.h>

#define BB 8
#define HH 512
#define WW 512
#define HW (HH * WW)
#define NPIX (BB * HH * WW)
#define NITEM (NPIX / 4)        // float4 items
#define NBLK (NITEM / 256)      // 2048 blocks

typedef __attribute__((ext_vector_type(4))) float f4;

__device__ __forceinline__ f4 ld4(const float* p) {
    return *reinterpret_cast<const f4*>(p);   // may be only 4B-aligned: gfx950 global loads tolerate it
}

__device__ __forceinline__ float clipf(float v) {
    // EPS = 1e-10; upper bound 1.0-1e-10 rounds to 1.0f in fp32.
    return fminf(fmaxf(v, 1e-10f), 1.0f);
}

__global__ __launch_bounds__(256) void loss_kernel(
    const float* __restrict__ roi,
    const float* __restrict__ hm0,
    const float* __restrict__ hm1,
    const float* __restrict__ hm2,
    const float* __restrict__ r1pf, const float* __restrict__ r1pb,
    const float* __restrict__ r1nf, const float* __restrict__ r1nb,
    const float* __restrict__ r0f,  const float* __restrict__ r0b,
    const float* __restrict__ r2f,  const float* __restrict__ r2b,
    const float* __restrict__ fA,   // flow_0_1f  (unshifted operand)
    const float* __restrict__ fAi,  // flow_1_0b  (shifted operand)
    const float* __restrict__ fB,   // flow_1_2f  (unshifted operand)
    const float* __restrict__ fBi,  // flow_2_1b  (shifted operand)
    float* __restrict__ partial)
{
    int t = blockIdx.x * blockDim.x + threadIdx.x;   // 0 .. NITEM-1
    int x0 = (t & 127) << 2;                         // aligned x of this float4
    int y  = (t >> 7) & (HH - 1);
    int b  = t >> 16;
    int idx = t << 2;

    f4 roiv = ld4(roi + idx);
    f4 h0 = ld4(hm0 + idx), h1 = ld4(hm1 + idx), h2 = ld4(hm2 + idx);
    f4 v1pf = ld4(r1pf + idx), v1pb = ld4(r1pb + idx);
    f4 v1nf = ld4(r1nf + idx), v1nb = ld4(r1nb + idx);
    f4 v0f  = ld4(r0f + idx),  v0b  = ld4(r0b + idx);
    f4 v2f  = ld4(r2f + idx),  v2b  = ld4(r2b + idx);

    float acc = 0.0f;
    #pragma unroll
    for (int j = 0; j < 4; ++j) {
        float pre  = fabsf(h0[j] - h1[j]);
        float post = fabsf(h1[j] - h2[j]);
        float w1 = roiv[j] * (1.0f + pre);   // RF = 1.0
        float w2 = roiv[j] * (1.0f + post);
        float d;
        float s1p = 0.f, s1n = 0.f, s0 = 0.f, s2 = 0.f;
        d = v1pf[j] - h1[j]; s1p += d * d;
        d = v1pb[j] - h1[j]; s1p += d * d;
        d = v1nf[j] - h1[j]; s1n += d * d;
        d = v1nb[j] - h1[j]; s1n += d * d;
        d = v0f[j]  - h0[j]; s0  += d * d;
        d = v0b[j]  - h0[j]; s0  += d * d;
        d = v2f[j]  - h2[j]; s2  += d * d;
        d = v2b[j]  - h2[j]; s2  += d * d;
        acc += 0.25f * (w1 * s1p + w2 * s1n) + 0.5f * (w1 * s0 + w2 * s2);
    }

    // Flow consistency: 9 channels x 2 flow pairs, weight 1/9, mask = roi at 'a' pos.
    // a = flow[b, i, y, x]; bv = flow_inv[b, 8-i, y-dy, x-dx]
    // Shifted loads (dx != 0) are 4B-aligned float4 loads; addresses never
    // leave the flow allocation (negative x-offset only at channel >= 2,
    // positive overflow spills into the next in-array row/channel).
    f4 cons = {0.f, 0.f, 0.f, 0.f};
    const int flowBase = b * 9 * HW;
    const int aOff = flowBase + y * WW + x0;
    #pragma unroll
    for (int i = 0; i < 9; ++i) {
        const int dy = (i < 3) ? 1 : (i < 6) ? 0 : -1;
        const int m  = i % 3;
        const int dx = (m == 0) ? 1 : (m == 1) ? 0 : -1;
        bool yvalid = ((unsigned)(y - dy) < (unsigned)HH);
        int ys = yvalid ? (y - dy) : y;
        const int bOff = flowBase + (8 - i) * HW + ys * WW + x0 - dx;

        f4 a1 = ld4(fA  + aOff + i * HW);
        f4 b1 = ld4(fAi + bOff);
        f4 a2 = ld4(fB  + aOff + i * HW);
        f4 b2 = ld4(fBi + bOff);

        float yv = yvalid ? 1.0f : 0.0f;
        #pragma unroll
        for (int j = 0; j < 4; ++j) {
            float xv = 1.0f;
            if (dx == 1  && (x0 + j) == 0)       xv = 0.0f;
            if (dx == -1 && (x0 + j) == WW - 1)  xv = 0.0f;
            float d1 = clipf(a1[j]) - clipf(b1[j]);
            float d2 = clipf(a2[j]) - clipf(b2[j]);
            cons[j] += (yv * xv) * (d1 * d1 + d2 * d2);
        }
    }
    #pragma unroll
    for (int j = 0; j < 4; ++j)
        acc += cons[j] * roiv[j] * (1.0f / 9.0f);

    // Wave-64 reduction -> LDS -> one partial per block (no atomics)
    #pragma unroll
    for (int off = 32; off > 0; off >>= 1)
        acc += __shfl_down(acc, off, 64);

    __shared__ float wsum[4];
    int lane = threadIdx.x & 63;
    int wid  = threadIdx.x >> 6;
    if (lane == 0) wsum[wid] = acc;
    __syncthreads();
    if (threadIdx.x == 0)
        partial[blockIdx.x] = wsum[0] + wsum[1] + wsum[2] + wsum[3];
}

__global__ __launch_bounds__(256) void finalize(const float* __restrict__ partial,
                                                float* __restrict__ out)
{
    double acc = 0.0;
    for (int i = threadIdx.x; i < NBLK; i += 256)
        acc += (double)partial[i];
    #pragma unroll
    for (int off = 32; off > 0; off >>= 1)
        acc += __shfl_down(acc, off, 64);
    __shared__ double wsum[4];
    int lane = threadIdx.x & 63;
    int wid  = threadIdx.x >> 6;
    if (lane == 0) wsum[wid] = acc;
    __syncthreads();
    if (threadIdx.x == 0)
        out[0] = (float)(wsum[0] + wsum[1] + wsum[2] + wsum[3]);
}

extern "C" void kernel_launch(void* const* d_in, const int* in_sizes, int n_in,
                              void* d_out, int out_size, void* d_ws, size_t ws_size,
                              hipStream_t stream) {
    const float* roi  = (const float*)d_in[0];
    // d_in[1] = boundary_mask: unused by the reference.
    const float* hm0  = (const float*)d_in[2];
    const float* hm1  = (const float*)d_in[3];
    const float* hm2  = (const float*)d_in[4];
    const float* r1pf = (const float*)d_in[5];
    const float* r1pb = (const float*)d_in[6];
    const float* r1nf = (const float*)d_in[7];
    const float* r1nb = (const float*)d_in[8];
    const float* r0f  = (const float*)d_in[9];
    const float* r0b  = (const float*)d_in[10];
    const float* r2f  = (const float*)d_in[11];
    const float* r2b  = (const float*)d_in[12];
    const float* fA   = (const float*)d_in[13];
    const float* fAi  = (const float*)d_in[14];
    const float* fB   = (const float*)d_in[15];
    const float* fBi  = (const float*)d_in[16];

    float* partial = (float*)d_ws;    // NBLK floats = 8 KB
    float* out = (float*)d_out;

    loss_kernel<<<NBLK, 256, 0, stream>>>(
        roi, hm0, hm1, hm2, r1pf, r1pb, r1nf, r1nb,
        r0f, r0b, r2f, r2b, fA, fAi, fB, fBi, partial);
    finalize<<<1, 256, 0, stream>>>(partial, out);
}

// Round 3
// 362.027 us; speedup vs baseline: 1.0540x; 1.0172x over previous
//
#include <hip/hip_runtime.h>

#define BB 8
#define HH 512
#define WW 512
#define HW (HH * WW)
#define NPIX (BB * HH * WW)
#define NITEM (NPIX / 4)        // float4 items
#define NBLK (NITEM / 256)      // 2048 blocks

typedef __attribute__((ext_vector_type(4))) float f4;

__device__ __forceinline__ f4 ld4(const float* p) {
    return *reinterpret_cast<const f4*>(p);   // may be only 4B-aligned: gfx950 global loads tolerate it
}

__device__ __forceinline__ float clipf(float v) {
    // EPS = 1e-10; upper bound 1.0-1e-10 rounds to 1.0f in fp32.
    return fminf(fmaxf(v, 1e-10f), 1.0f);
}

// __launch_bounds__(256, 2): min 2 waves/EU -> VGPR cap 256. R2's counter
// showed VGPR_Count=32 (compiler went for 8 waves/EU), which serialized the
// 48 loads/thread into register-reuse batches -> latency-bound at 20% HBM.
__global__ __launch_bounds__(256, 2) void loss_kernel(
    const float* __restrict__ roi,
    const float* __restrict__ hm0,
    const float* __restrict__ hm1,
    const float* __restrict__ hm2,
    const float* __restrict__ r1pf, const float* __restrict__ r1pb,
    const float* __restrict__ r1nf, const float* __restrict__ r1nb,
    const float* __restrict__ r0f,  const float* __restrict__ r0b,
    const float* __restrict__ r2f,  const float* __restrict__ r2b,
    const float* __restrict__ fA,   // flow_0_1f  (unshifted operand)
    const float* __restrict__ fAi,  // flow_1_0b  (shifted operand)
    const float* __restrict__ fB,   // flow_1_2f  (unshifted operand)
    const float* __restrict__ fBi,  // flow_2_1b  (shifted operand)
    float* __restrict__ partial)
{
    int t = blockIdx.x * blockDim.x + threadIdx.x;   // 0 .. NITEM-1
    int x0 = (t & 127) << 2;                         // aligned x of this float4
    int y  = (t >> 7) & (HH - 1);
    int b  = t >> 16;
    int idx = t << 2;

    // ---- Phase 1: heatmap/reconstruction terms (12 float4 loads in flight) ----
    f4 roiv = ld4(roi + idx);
    f4 h0 = ld4(hm0 + idx), h1 = ld4(hm1 + idx), h2 = ld4(hm2 + idx);
    f4 v1pf = ld4(r1pf + idx), v1pb = ld4(r1pb + idx);
    f4 v1nf = ld4(r1nf + idx), v1nb = ld4(r1nb + idx);
    f4 v0f  = ld4(r0f + idx),  v0b  = ld4(r0b + idx);
    f4 v2f  = ld4(r2f + idx),  v2b  = ld4(r2b + idx);

    float acc = 0.0f;
    #pragma unroll
    for (int j = 0; j < 4; ++j) {
        float pre  = fabsf(h0[j] - h1[j]);
        float post = fabsf(h1[j] - h2[j]);
        float w1 = roiv[j] * (1.0f + pre);   // RF = 1.0
        float w2 = roiv[j] * (1.0f + post);
        float d;
        float s1p = 0.f, s1n = 0.f, s0 = 0.f, s2 = 0.f;
        d = v1pf[j] - h1[j]; s1p += d * d;
        d = v1pb[j] - h1[j]; s1p += d * d;
        d = v1nf[j] - h1[j]; s1n += d * d;
        d = v1nb[j] - h1[j]; s1n += d * d;
        d = v0f[j]  - h0[j]; s0  += d * d;
        d = v0b[j]  - h0[j]; s0  += d * d;
        d = v2f[j]  - h2[j]; s2  += d * d;
        d = v2b[j]  - h2[j]; s2  += d * d;
        acc += 0.25f * (w1 * s1p + w2 * s1n) + 0.5f * (w1 * s0 + w2 * s2);
    }

    // ---- Phase 2: flow consistency. Issue ALL 36 float4 loads into register
    // arrays first (144 VGPRs of data), then compute. dx!=0 loads are 4B-aligned
    // float4 loads; addresses never leave the flow allocation.
    f4 a1[9], b1[9], a2[9], b2[9];
    const int flowBase = b * 9 * HW;
    const int aOff = flowBase + y * WW + x0;
    #pragma unroll
    for (int i = 0; i < 9; ++i) {
        const int dy = (i < 3) ? 1 : (i < 6) ? 0 : -1;
        const int m  = i % 3;
        const int dx = (m == 0) ? 1 : (m == 1) ? 0 : -1;
        bool yvalid = ((unsigned)(y - dy) < (unsigned)HH);
        int ys = yvalid ? (y - dy) : y;
        const int bOff = flowBase + (8 - i) * HW + ys * WW + x0 - dx;
        a1[i] = ld4(fA  + aOff + i * HW);
        b1[i] = ld4(fAi + bOff);
        a2[i] = ld4(fB  + aOff + i * HW);
        b2[i] = ld4(fBi + bOff);
    }

    f4 cons = {0.f, 0.f, 0.f, 0.f};
    #pragma unroll
    for (int i = 0; i < 9; ++i) {
        const int dy = (i < 3) ? 1 : (i < 6) ? 0 : -1;
        const int m  = i % 3;
        const int dx = (m == 0) ? 1 : (m == 1) ? 0 : -1;
        float yv = ((unsigned)(y - dy) < (unsigned)HH) ? 1.0f : 0.0f;
        #pragma unroll
        for (int j = 0; j < 4; ++j) {
            float xv = 1.0f;
            if (dx == 1  && (x0 + j) == 0)       xv = 0.0f;
            if (dx == -1 && (x0 + j) == WW - 1)  xv = 0.0f;
            float d1 = clipf(a1[i][j]) - clipf(b1[i][j]);
            float d2 = clipf(a2[i][j]) - clipf(b2[i][j]);
            cons[j] += (yv * xv) * (d1 * d1 + d2 * d2);
        }
    }
    #pragma unroll
    for (int j = 0; j < 4; ++j)
        acc += cons[j] * roiv[j] * (1.0f / 9.0f);

    // Wave-64 reduction -> LDS -> one partial per block (no atomics)
    #pragma unroll
    for (int off = 32; off > 0; off >>= 1)
        acc += __shfl_down(acc, off, 64);

    __shared__ float wsum[4];
    int lane = threadIdx.x & 63;
    int wid  = threadIdx.x >> 6;
    if (lane == 0) wsum[wid] = acc;
    __syncthreads();
    if (threadIdx.x == 0)
        partial[blockIdx.x] = wsum[0] + wsum[1] + wsum[2] + wsum[3];
}

__global__ __launch_bounds__(256) void finalize(const float* __restrict__ partial,
                                                float* __restrict__ out)
{
    double acc = 0.0;
    for (int i = threadIdx.x; i < NBLK; i += 256)
        acc += (double)partial[i];
    #pragma unroll
    for (int off = 32; off > 0; off >>= 1)
        acc += __shfl_down(acc, off, 64);
    __shared__ double wsum[4];
    int lane = threadIdx.x & 63;
    int wid  = threadIdx.x >> 6;
    if (lane == 0) wsum[wid] = acc;
    __syncthreads();
    if (threadIdx.x == 0)
        out[0] = (float)(wsum[0] + wsum[1] + wsum[2] + wsum[3]);
}

extern "C" void kernel_launch(void* const* d_in, const int* in_sizes, int n_in,
                              void* d_out, int out_size, void* d_ws, size_t ws_size,
                              hipStream_t stream) {
    const float* roi  = (const float*)d_in[0];
    // d_in[1] = boundary_mask: unused by the reference.
    const float* hm0  = (const float*)d_in[2];
    const float* hm1  = (const float*)d_in[3];
    const float* hm2  = (const float*)d_in[4];
    const float* r1pf = (const float*)d_in[5];
    const float* r1pb = (const float*)d_in[6];
    const float* r1nf = (const float*)d_in[7];
    const float* r1nb = (const float*)d_in[8];
    const float* r0f  = (const float*)d_in[9];
    const float* r0b  = (const float*)d_in[10];
    const float* r2f  = (const float*)d_in[11];
    const float* r2b  = (const float*)d_in[12];
    const float* fA   = (const float*)d_in[13];
    const float* fAi  = (const float*)d_in[14];
    const float* fB   = (const float*)d_in[15];
    const float* fBi  = (const float*)d_in[16];

    float* partial = (float*)d_ws;    // NBLK floats = 8 KB
    float* out = (float*)d_out;

    loss_kernel<<<NBLK, 256, 0, stream>>>(
        roi, hm0, hm1, hm2, r1pf, r1pb, r1nf, r1nb,
        r0f, r0b, r2f, r2b, fA, fAi, fB, fBi, partial);
    finalize<<<1, 256, 0, stream>>>(partial, out);
}

// Round 4
// 329.876 us; speedup vs baseline: 1.1567x; 1.0975x over previous
//
#include <hip/hip_runtime.h>

#define BB 8
#define HH 512
#define WW 512
#define HW (HH * WW)
#define NPIX (BB * HH * WW)
#define NITEM (NPIX / 4)        // float4 items
#define NBLK (NITEM / 256)      // 2048 blocks

typedef __attribute__((ext_vector_type(4))) float f4;

__device__ __forceinline__ f4 ld4(const float* p) {
    // Non-temporal: skip L1 allocation. Theory: per-CU L1 streaming-miss
    // (line-fill) path is the ~5 B/cyc/CU wall seen in R1-R3.
    return __builtin_nontemporal_load(reinterpret_cast<const f4*>(p));
}

__device__ __forceinline__ float clipf(float v) {
    // EPS = 1e-10; upper bound 1.0-1e-10 rounds to 1.0f in fp32.
    return fminf(fmaxf(v, 1e-10f), 1.0f);
}

__global__ __launch_bounds__(256, 2) void loss_kernel(
    const float* __restrict__ roi,
    const float* __restrict__ hm0,
    const float* __restrict__ hm1,
    const float* __restrict__ hm2,
    const float* __restrict__ r1pf, const float* __restrict__ r1pb,
    const float* __restrict__ r1nf, const float* __restrict__ r1nb,
    const float* __restrict__ r0f,  const float* __restrict__ r0b,
    const float* __restrict__ r2f,  const float* __restrict__ r2b,
    const float* __restrict__ fA,   // flow_0_1f  (unshifted operand)
    const float* __restrict__ fAi,  // flow_1_0b  (shifted operand)
    const float* __restrict__ fB,   // flow_1_2f  (unshifted operand)
    const float* __restrict__ fBi,  // flow_2_1b  (shifted operand)
    float* __restrict__ partial)
{
    int t = blockIdx.x * blockDim.x + threadIdx.x;   // 0 .. NITEM-1
    int x0 = (t & 127) << 2;                         // aligned x of this float4
    int y  = (t >> 7) & (HH - 1);
    int b  = t >> 16;
    int idx = t << 2;

    // ---- Phase 1: heatmap/reconstruction terms (12 float4 loads in flight) ----
    f4 roiv = ld4(roi + idx);
    f4 h0 = ld4(hm0 + idx), h1 = ld4(hm1 + idx), h2 = ld4(hm2 + idx);
    f4 v1pf = ld4(r1pf + idx), v1pb = ld4(r1pb + idx);
    f4 v1nf = ld4(r1nf + idx), v1nb = ld4(r1nb + idx);
    f4 v0f  = ld4(r0f + idx),  v0b  = ld4(r0b + idx);
    f4 v2f  = ld4(r2f + idx),  v2b  = ld4(r2b + idx);

    float acc = 0.0f;
    #pragma unroll
    for (int j = 0; j < 4; ++j) {
        float pre  = fabsf(h0[j] - h1[j]);
        float post = fabsf(h1[j] - h2[j]);
        float w1 = roiv[j] * (1.0f + pre);   // RF = 1.0
        float w2 = roiv[j] * (1.0f + post);
        float d;
        float s1p = 0.f, s1n = 0.f, s0 = 0.f, s2 = 0.f;
        d = v1pf[j] - h1[j]; s1p += d * d;
        d = v1pb[j] - h1[j]; s1p += d * d;
        d = v1nf[j] - h1[j]; s1n += d * d;
        d = v1nb[j] - h1[j]; s1n += d * d;
        d = v0f[j]  - h0[j]; s0  += d * d;
        d = v0b[j]  - h0[j]; s0  += d * d;
        d = v2f[j]  - h2[j]; s2  += d * d;
        d = v2b[j]  - h2[j]; s2  += d * d;
        acc += 0.25f * (w1 * s1p + w2 * s1n) + 0.5f * (w1 * s0 + w2 * s2);
    }

    // ---- Phase 2: flow consistency. 36 float4 loads batched into register
    // arrays, then compute. dx!=0 loads are 4B-aligned float4 loads; addresses
    // never leave the flow allocation.
    f4 a1[9], b1[9], a2[9], b2[9];
    const int flowBase = b * 9 * HW;
    const int aOff = flowBase + y * WW + x0;
    #pragma unroll
    for (int i = 0; i < 9; ++i) {
        const int dy = (i < 3) ? 1 : (i < 6) ? 0 : -1;
        const int m  = i % 3;
        const int dx = (m == 0) ? 1 : (m == 1) ? 0 : -1;
        bool yvalid = ((unsigned)(y - dy) < (unsigned)HH);
        int ys = yvalid ? (y - dy) : y;
        const int bOff = flowBase + (8 - i) * HW + ys * WW + x0 - dx;
        a1[i] = ld4(fA  + aOff + i * HW);
        b1[i] = ld4(fAi + bOff);
        a2[i] = ld4(fB  + aOff + i * HW);
        b2[i] = ld4(fBi + bOff);
    }

    f4 cons = {0.f, 0.f, 0.f, 0.f};
    #pragma unroll
    for (int i = 0; i < 9; ++i) {
        const int dy = (i < 3) ? 1 : (i < 6) ? 0 : -1;
        const int m  = i % 3;
        const int dx = (m == 0) ? 1 : (m == 1) ? 0 : -1;
        float yv = ((unsigned)(y - dy) < (unsigned)HH) ? 1.0f : 0.0f;
        #pragma unroll
        for (int j = 0; j < 4; ++j) {
            float xv = 1.0f;
            if (dx == 1  && (x0 + j) == 0)       xv = 0.0f;
            if (dx == -1 && (x0 + j) == WW - 1)  xv = 0.0f;
            float d1 = clipf(a1[i][j]) - clipf(b1[i][j]);
            float d2 = clipf(a2[i][j]) - clipf(b2[i][j]);
            cons[j] += (yv * xv) * (d1 * d1 + d2 * d2);
        }
    }
    #pragma unroll
    for (int j = 0; j < 4; ++j)
        acc += cons[j] * roiv[j] * (1.0f / 9.0f);

    // Wave-64 reduction -> LDS -> one partial per block (no atomics)
    #pragma unroll
    for (int off = 32; off > 0; off >>= 1)
        acc += __shfl_down(acc, off, 64);

    __shared__ float wsum[4];
    int lane = threadIdx.x & 63;
    int wid  = threadIdx.x >> 6;
    if (lane == 0) wsum[wid] = acc;
    __syncthreads();
    if (threadIdx.x == 0)
        partial[blockIdx.x] = wsum[0] + wsum[1] + wsum[2] + wsum[3];
}

__global__ __launch_bounds__(256) void finalize(const float* __restrict__ partial,
                                                float* __restrict__ out)
{
    double acc = 0.0;
    for (int i = threadIdx.x; i < NBLK; i += 256)
        acc += (double)partial[i];
    #pragma unroll
    for (int off = 32; off > 0; off >>= 1)
        acc += __shfl_down(acc, off, 64);
    __shared__ double wsum[4];
    int lane = threadIdx.x & 63;
    int wid  = threadIdx.x >> 6;
    if (lane == 0) wsum[wid] = acc;
    __syncthreads();
    if (threadIdx.x == 0)
        out[0] = (float)(wsum[0] + wsum[1] + wsum[2] + wsum[3]);
}

extern "C" void kernel_launch(void* const* d_in, const int* in_sizes, int n_in,
                              void* d_out, int out_size, void* d_ws, size_t ws_size,
                              hipStream_t stream) {
    const float* roi  = (const float*)d_in[0];
    // d_in[1] = boundary_mask: unused by the reference.
    const float* hm0  = (const float*)d_in[2];
    const float* hm1  = (const float*)d_in[3];
    const float* hm2  = (const float*)d_in[4];
    const float* r1pf = (const float*)d_in[5];
    const float* r1pb = (const float*)d_in[6];
    const float* r1nf = (const float*)d_in[7];
    const float* r1nb = (const float*)d_in[8];
    const float* r0f  = (const float*)d_in[9];
    const float* r0b  = (const float*)d_in[10];
    const float* r2f  = (const float*)d_in[11];
    const float* r2b  = (const float*)d_in[12];
    const float* fA   = (const float*)d_in[13];
    const float* fAi  = (const float*)d_in[14];
    const float* fB   = (const float*)d_in[15];
    const float* fBi  = (const float*)d_in[16];

    float* partial = (float*)d_ws;    // NBLK floats = 8 KB
    float* out = (float*)d_out;

    loss_kernel<<<NBLK, 256, 0, stream>>>(
        roi, hm0, hm1, hm2, r1pf, r1pb, r1nf, r1nb,
        r0f, r0b, r2f, r2b, fA, fAi, fB, fBi, partial);
    finalize<<<1, 256, 0, stream>>>(partial, out);
}

// Round 5
// 329.366 us; speedup vs baseline: 1.1585x; 1.0015x over previous
//
#include <hip/hip_runtime.h>

#define BB 8
#define HH 512
#define WW 512
#define HW (HH * WW)
#define NPIX (BB * HH * WW)
#define NITEM (NPIX / 4)        // float4 items
#define NBLK (NITEM / 256)      // 2048 blocks

typedef __attribute__((ext_vector_type(4))) float f4;

__device__ __forceinline__ f4 ld4(const float* p) {
    // Non-temporal: skip L1 allocation. R4 confirmed: L1 line-fill was the
    // ~5 B/cyc/CU wall (125 -> 68 us).
    return __builtin_nontemporal_load(reinterpret_cast<const f4*>(p));
}

__device__ __forceinline__ float clipf(float v) {
    // EPS = 1e-10; upper bound 1.0-1e-10 rounds to 1.0f in fp32.
    return fminf(fmaxf(v, 1e-10f), 1.0f);
}

// All 48 float4 loads issued up front: phase-1 compute can run at vmcnt(36)
// while flow loads are still in flight -> no request-stream dip at the
// phase boundary. launch_bounds(256,2) -> 256-VGPR cap, no spill at ~210.
__global__ __launch_bounds__(256, 2) void loss_kernel(
    const float* __restrict__ roi,
    const float* __restrict__ hm0,
    const float* __restrict__ hm1,
    const float* __restrict__ hm2,
    const float* __restrict__ r1pf, const float* __restrict__ r1pb,
    const float* __restrict__ r1nf, const float* __restrict__ r1nb,
    const float* __restrict__ r0f,  const float* __restrict__ r0b,
    const float* __restrict__ r2f,  const float* __restrict__ r2b,
    const float* __restrict__ fA,   // flow_0_1f  (unshifted operand)
    const float* __restrict__ fAi,  // flow_1_0b  (shifted operand)
    const float* __restrict__ fB,   // flow_1_2f  (unshifted operand)
    const float* __restrict__ fBi,  // flow_2_1b  (shifted operand)
    float* __restrict__ partial)
{
    int t = blockIdx.x * blockDim.x + threadIdx.x;   // 0 .. NITEM-1
    int x0 = (t & 127) << 2;                         // aligned x of this float4
    int y  = (t >> 7) & (HH - 1);
    int b  = t >> 16;
    int idx = t << 2;

    // ---- Issue ALL loads first (12 heatmap + 36 flow) ----
    f4 roiv = ld4(roi + idx);
    f4 h0 = ld4(hm0 + idx), h1 = ld4(hm1 + idx), h2 = ld4(hm2 + idx);
    f4 v1pf = ld4(r1pf + idx), v1pb = ld4(r1pb + idx);
    f4 v1nf = ld4(r1nf + idx), v1nb = ld4(r1nb + idx);
    f4 v0f  = ld4(r0f + idx),  v0b  = ld4(r0b + idx);
    f4 v2f  = ld4(r2f + idx),  v2b  = ld4(r2b + idx);

    // Flow loads: dx!=0 are 4B-aligned float4 loads; addresses never leave
    // the flow allocation (negative x-offset only at channel >= 2, positive
    // overflow spills into the next in-array row/channel).
    f4 a1[9], b1[9], a2[9], b2[9];
    const int flowBase = b * 9 * HW;
    const int aOff = flowBase + y * WW + x0;
    #pragma unroll
    for (int i = 0; i < 9; ++i) {
        const int dy = (i < 3) ? 1 : (i < 6) ? 0 : -1;
        const int m  = i % 3;
        const int dx = (m == 0) ? 1 : (m == 1) ? 0 : -1;
        bool yvalid = ((unsigned)(y - dy) < (unsigned)HH);
        int ys = yvalid ? (y - dy) : y;
        const int bOff = flowBase + (8 - i) * HW + ys * WW + x0 - dx;
        a1[i] = ld4(fA  + aOff + i * HW);
        b1[i] = ld4(fAi + bOff);
        a2[i] = ld4(fB  + aOff + i * HW);
        b2[i] = ld4(fBi + bOff);
    }

    // ---- Phase 1 compute (needs only the first 12 loads) ----
    float acc = 0.0f;
    #pragma unroll
    for (int j = 0; j < 4; ++j) {
        float pre  = fabsf(h0[j] - h1[j]);
        float post = fabsf(h1[j] - h2[j]);
        float w1 = roiv[j] * (1.0f + pre);   // RF = 1.0
        float w2 = roiv[j] * (1.0f + post);
        float d;
        float s1p = 0.f, s1n = 0.f, s0 = 0.f, s2 = 0.f;
        d = v1pf[j] - h1[j]; s1p += d * d;
        d = v1pb[j] - h1[j]; s1p += d * d;
        d = v1nf[j] - h1[j]; s1n += d * d;
        d = v1nb[j] - h1[j]; s1n += d * d;
        d = v0f[j]  - h0[j]; s0  += d * d;
        d = v0b[j]  - h0[j]; s0  += d * d;
        d = v2f[j]  - h2[j]; s2  += d * d;
        d = v2b[j]  - h2[j]; s2  += d * d;
        acc += 0.25f * (w1 * s1p + w2 * s1n) + 0.5f * (w1 * s0 + w2 * s2);
    }

    // ---- Phase 2 compute ----
    f4 cons = {0.f, 0.f, 0.f, 0.f};
    #pragma unroll
    for (int i = 0; i < 9; ++i) {
        const int dy = (i < 3) ? 1 : (i < 6) ? 0 : -1;
        const int m  = i % 3;
        const int dx = (m == 0) ? 1 : (m == 1) ? 0 : -1;
        float yv = ((unsigned)(y - dy) < (unsigned)HH) ? 1.0f : 0.0f;
        #pragma unroll
        for (int j = 0; j < 4; ++j) {
            float xv = 1.0f;
            if (dx == 1  && (x0 + j) == 0)       xv = 0.0f;
            if (dx == -1 && (x0 + j) == WW - 1)  xv = 0.0f;
            float d1 = clipf(a1[i][j]) - clipf(b1[i][j]);
            float d2 = clipf(a2[i][j]) - clipf(b2[i][j]);
            cons[j] += (yv * xv) * (d1 * d1 + d2 * d2);
        }
    }
    #pragma unroll
    for (int j = 0; j < 4; ++j)
        acc += cons[j] * roiv[j] * (1.0f / 9.0f);

    // Wave-64 reduction -> LDS -> one partial per block (no atomics)
    #pragma unroll
    for (int off = 32; off > 0; off >>= 1)
        acc += __shfl_down(acc, off, 64);

    __shared__ float wsum[4];
    int lane = threadIdx.x & 63;
    int wid  = threadIdx.x >> 6;
    if (lane == 0) wsum[wid] = acc;
    __syncthreads();
    if (threadIdx.x == 0)
        partial[blockIdx.x] = wsum[0] + wsum[1] + wsum[2] + wsum[3];
}

__global__ __launch_bounds__(256) void finalize(const float* __restrict__ partial,
                                                float* __restrict__ out)
{
    double acc = 0.0;
    for (int i = threadIdx.x; i < NBLK; i += 256)
        acc += (double)partial[i];
    #pragma unroll
    for (int off = 32; off > 0; off >>= 1)
        acc += __shfl_down(acc, off, 64);
    __shared__ double wsum[4];
    int lane = threadIdx.x & 63;
    int wid  = threadIdx.x >> 6;
    if (lane == 0) wsum[wid] = acc;
    __syncthreads();
    if (threadIdx.x == 0)
        out[0] = (float)(wsum[0] + wsum[1] + wsum[2] + wsum[3]);
}

extern "C" void kernel_launch(void* const* d_in, const int* in_sizes, int n_in,
                              void* d_out, int out_size, void* d_ws, size_t ws_size,
                              hipStream_t stream) {
    const float* roi  = (const float*)d_in[0];
    // d_in[1] = boundary_mask: unused by the reference.
    const float* hm0  = (const float*)d_in[2];
    const float* hm1  = (const float*)d_in[3];
    const float* hm2  = (const float*)d_in[4];
    const float* r1pf = (const float*)d_in[5];
    const float* r1pb = (const float*)d_in[6];
    const float* r1nf = (const float*)d_in[7];
    const float* r1nb = (const float*)d_in[8];
    const float* r0f  = (const float*)d_in[9];
    const float* r0b  = (const float*)d_in[10];
    const float* r2f  = (const float*)d_in[11];
    const float* r2b  = (const float*)d_in[12];
    const float* fA   = (const float*)d_in[13];
    const float* fAi  = (const float*)d_in[14];
    const float* fB   = (const float*)d_in[15];
    const float* fBi  = (const float*)d_in[16];

    float* partial = (float*)d_ws;    // NBLK floats = 8 KB
    float* out = (float*)d_out;

    loss_kernel<<<NBLK, 256, 0, stream>>>(
        roi, hm0, hm1, hm2, r1pf, r1pb, r1nf, r1nb,
        r0f, r0b, r2f, r2b, fA, fAi, fB, fBi, partial);
    finalize<<<1, 256, 0, stream>>>(partial, out);
}